// Round 12
// baseline (4372.198 us; speedup 1.0000x reference)
//
#include <hip/hip_runtime.h>

// Problem constants (fixed by reference)
#define BB 256      // batch
#define TT 1024     // time steps
#define HH 32       // hidden
#define SS 8        // superstep length (steps per barrier)
#define NBK (TT/SS) // 128 blocks
#define NSS (NBK+9) // 137 supersteps (10-stage skew)
#define NT 1024     // 16 waves (6 idle, kept for SIMD balance)
#define XS 12       // transposed stream row stride (floats): [32 units][SS t]+pad
#define GP 96       // gib row stride

// Superstep n (stage s handles 8-step block n-s; one barrier per superstep):
//   wv15(S3): emb gather blk n      -> ebufT   (transposed [k][t])
//   wv3 (S3): y1  blk n-1           -> y1sT    (transposed-ILP, no rlanes)
//   wv7 (S3): y2  blk n-2           -> y2sT
//   wv11(S3): y3  blk n-3           -> y3sT
//   wv6 (S2): gi0 blk n-4           -> gib[0]  (transposed-ILP)
//   wv0 (S0): gh0+gates blk n-5     -> h0sT    (8 serial steps, h in regs)
//   wv4 (S0): gi1 blk n-6           -> gib[1]
//   wv1 (S1): gh1+gates blk n-7     -> h1sT
//   wv5 (S1): gi2 blk n-8           -> gib[2]
//   wv2 (S2): gh2+gates blk n-9     -> out_seq
//   wv8,9,10,12,13,14: idle (barrier only)
// Feed-forward waves read x via uniform-address b128 broadcasts (2 per k)
// instead of 32 v_readlane per step: kills ~40% of total VALU issue.

__device__ __forceinline__ float fast_rcp(float x) { return __builtin_amdgcn_rcpf(x); }
__device__ __forceinline__ float sigm(float x)     { return fast_rcp(1.f + __expf(-x)); }
__device__ __forceinline__ float tanh_fast(float x){ float e = __expf(2.f * x); return 1.f - 2.f * fast_rcp(e + 1.f); }
__device__ __forceinline__ float rlane(float v, int k) {
    return __int_as_float(__builtin_amdgcn_readlane(__float_as_int(v), k));
}

__global__ __launch_bounds__(NT, 4) void rnn_fused(
    const int*   __restrict__ xidx,   // [B,T]
    const float* __restrict__ hid,    // [L,B,H]
    const float* __restrict__ emb,    // [38000,H]
    const float* __restrict__ W1, const float* __restrict__ b1,
    const float* __restrict__ W2, const float* __restrict__ b2,
    const float* __restrict__ W3, const float* __restrict__ b3,
    const float* __restrict__ Wih,    // [L,3H,H]
    const float* __restrict__ Whh,    // [L,3H,H]
    const float* __restrict__ bih,    // [L,3H]
    const float* __restrict__ bhh,    // [L,3H]
    float*       __restrict__ out)    // [B*T*H] ++ [L*B*H]
{
    const int b   = blockIdx.x;
    const int tid = threadIdx.x;
    const int wv  = tid >> 6;
    const int ln  = tid & 63;
    const int lo  = ln & 31;

    __shared__ alignas(16) float ebufT[2][HH][XS];   // transposed streams [unit][t]
    __shared__ alignas(16) float y1sT [2][HH][XS];
    __shared__ alignas(16) float y2sT [2][HH][XS];
    __shared__ alignas(16) float y3sT [2][HH][XS];
    __shared__ alignas(16) float h0sT [2][HH][XS];
    __shared__ alignas(16) float h1sT [2][HH][XS];
    __shared__ alignas(16) float gib  [3][2][SS][GP];  // normal layout [t][row]

    // ---- roles ----
    const bool isGH = (wv < 3);
    const bool isGI = (wv >= 4 && wv < 7);
    const bool isY  = (wv == 3 || wv == 7 || wv == 11);
    const bool isE  = (wv == 15);
    const int  il   = (wv == 6) ? 0 : (wv == 4) ? 1 : 2;   // gi layer
    const int  ys   = (wv == 3) ? 0 : (wv == 7) ? 1 : 2;   // y stage

    // ---- register-resident weights ----
    float wA[32], wB[32];
    float biasA = 0.f, biasB = 0.f, v_h = 0.f;

    if (isGH) {
        const float4* pA = reinterpret_cast<const float4*>(Whh + (size_t)(wv * 96 + ln) * HH);
        const float4* pB = reinterpret_cast<const float4*>(Whh + (size_t)(wv * 96 + 64 + lo) * HH);
        #pragma unroll
        for (int i = 0; i < 8; ++i) {
            reinterpret_cast<float4*>(wA)[i] = pA[i];
            reinterpret_cast<float4*>(wB)[i] = pB[i];
        }
        biasA = bhh[wv * 96 + ln];
        biasB = bhh[wv * 96 + 64 + lo];
        if (ln < HH) v_h = hid[(size_t)(wv * BB + b) * HH + ln];
    } else if (isGI) {
        const float4* pA = reinterpret_cast<const float4*>(Wih + (size_t)(il * 96 + ln) * HH);
        const float4* pB = reinterpret_cast<const float4*>(Wih + (size_t)(il * 96 + 64 + lo) * HH);
        #pragma unroll
        for (int i = 0; i < 8; ++i) {
            reinterpret_cast<float4*>(wA)[i] = pA[i];
            reinterpret_cast<float4*>(wB)[i] = pB[i];
        }
        biasA = bih[il * 96 + ln];
        biasB = bih[il * 96 + 64 + lo];
    } else if (isY) {
        const float* Ws = (ys == 0) ? W1 : (ys == 1) ? W2 : W3;
        const float* bs = (ys == 0) ? b1 : (ys == 1) ? b2 : b3;
        const float4* pA = reinterpret_cast<const float4*>(Ws + (size_t)lo * HH);
        #pragma unroll
        for (int i = 0; i < 8; ++i) reinterpret_cast<float4*>(wA)[i] = pA[i];
        biasA = bs[lo];
    }
    __syncthreads();

    float* const out_seq = out + (size_t)b * TT * HH;
    float* const out_hf  = out + (size_t)BB * TT * HH;

    for (int n = 0; n < NSS; ++n) {
        if (isGH) {
            // ====== gh wave, layer wv: 8 serial recurrence steps ======
            const int blk = n - 5 - 2 * wv;
            if (blk >= 0 && blk < NBK) {
                const int p = blk & 1;
                const float* gsrc = &gib[wv][p][0][0];
                for (int t2 = 0; t2 < SS; ++t2) {
                    const float giA = gsrc[t2 * GP + ln];        // r/z rows (bih incl.)
                    const float giB = gsrc[t2 * GP + 64 + lo];   // n rows
                    float a0 = biasA, a1 = 0.f, c0 = biasB, c1 = 0.f;
                    #pragma unroll
                    for (int k = 0; k < 32; k += 2) {
                        const float h0 = rlane(v_h, k), h1 = rlane(v_h, k + 1);
                        a0 = fmaf(wA[k],     h0, a0);
                        a1 = fmaf(wA[k + 1], h1, a1);
                        c0 = fmaf(wB[k],     h0, c0);
                        c1 = fmaf(wB[k + 1], h1, c1);
                    }
                    const float sA  = giA + a0 + a1;     // r-pre / z-pre
                    const float ghB = c0 + c1;           // h_n
                    const float zp  = __shfl_xor(sA, 32);
                    const float r   = sigm(sA);
                    const float z   = sigm(zp);
                    const float nn  = tanh_fast(fmaf(r, ghB, giB));
                    const float hn  = fmaf(z, v_h - nn, nn);
                    v_h = hn;
                    if (ln < HH) {
                        if (wv == 0)      h0sT[p][ln][t2] = hn;   // transposed store
                        else if (wv == 1) h1sT[p][ln][t2] = hn;
                        else out_seq[(size_t)(blk * SS + t2) * HH + ln] = hn;
                    }
                }
            }
        } else if (isGI) {
            // ====== gi wave, layer il: transposed-ILP, zero rlanes ======
            const int blk = n - 4 - 2 * il;
            if (blk >= 0 && blk < NBK) {
                const int p = blk & 1;
                const float* xT = (il == 0) ? &y3sT[p][0][0]
                                : (il == 1) ? &h0sT[p][0][0]
                                            : &h1sT[p][0][0];
                float accA[SS], accB[SS];
                #pragma unroll
                for (int t = 0; t < SS; ++t) { accA[t] = biasA; accB[t] = biasB; }
                #pragma unroll
                for (int k = 0; k < 32; ++k) {   // fully unrolled: wA[k]/wB[k] static
                    const float4 xa = *reinterpret_cast<const float4*>(xT + k * XS);
                    const float4 xb = *reinterpret_cast<const float4*>(xT + k * XS + 4);
                    accA[0] = fmaf(wA[k], xa.x, accA[0]);
                    accA[1] = fmaf(wA[k], xa.y, accA[1]);
                    accA[2] = fmaf(wA[k], xa.z, accA[2]);
                    accA[3] = fmaf(wA[k], xa.w, accA[3]);
                    accA[4] = fmaf(wA[k], xb.x, accA[4]);
                    accA[5] = fmaf(wA[k], xb.y, accA[5]);
                    accA[6] = fmaf(wA[k], xb.z, accA[6]);
                    accA[7] = fmaf(wA[k], xb.w, accA[7]);
                    accB[0] = fmaf(wB[k], xa.x, accB[0]);
                    accB[1] = fmaf(wB[k], xa.y, accB[1]);
                    accB[2] = fmaf(wB[k], xa.z, accB[2]);
                    accB[3] = fmaf(wB[k], xa.w, accB[3]);
                    accB[4] = fmaf(wB[k], xb.x, accB[4]);
                    accB[5] = fmaf(wB[k], xb.y, accB[5]);
                    accB[6] = fmaf(wB[k], xb.z, accB[6]);
                    accB[7] = fmaf(wB[k], xb.w, accB[7]);
                }
                float* gdst = &gib[il][p][0][0];
                #pragma unroll
                for (int t = 0; t < SS; ++t) gdst[t * GP + ln] = accA[t];
                if (ln < 32) {
                    #pragma unroll
                    for (int t = 0; t < SS; ++t) gdst[t * GP + 64 + ln] = accB[t];
                }
            }
        } else if (isY) {
            // ====== y wave, stage ys: transposed-ILP, zero rlanes ======
            const int blk = n - 1 - ys;
            if (blk >= 0 && blk < NBK) {
                const int p = blk & 1;
                const float* xT = (ys == 0) ? &ebufT[p][0][0]
                                : (ys == 1) ? &y1sT[p][0][0]
                                            : &y2sT[p][0][0];
                float* dT = (ys == 0) ? &y1sT[p][0][0]
                          : (ys == 1) ? &y2sT[p][0][0]
                                      : &y3sT[p][0][0];
                float acc[SS];
                #pragma unroll
                for (int t = 0; t < SS; ++t) acc[t] = biasA;
                #pragma unroll
                for (int k = 0; k < 32; ++k) {
                    const float4 xa = *reinterpret_cast<const float4*>(xT + k * XS);
                    const float4 xb = *reinterpret_cast<const float4*>(xT + k * XS + 4);
                    acc[0] = fmaf(wA[k], xa.x, acc[0]);
                    acc[1] = fmaf(wA[k], xa.y, acc[1]);
                    acc[2] = fmaf(wA[k], xa.z, acc[2]);
                    acc[3] = fmaf(wA[k], xa.w, acc[3]);
                    acc[4] = fmaf(wA[k], xb.x, acc[4]);
                    acc[5] = fmaf(wA[k], xb.y, acc[5]);
                    acc[6] = fmaf(wA[k], xb.z, acc[6]);
                    acc[7] = fmaf(wA[k], xb.w, acc[7]);
                }
                if (ln < 32) {
                    #pragma unroll
                    for (int t = 0; t < SS; ++t)
                        dT[lo * XS + t] = fmaxf(acc[t], 0.f);   // row lo, transposed
                }
            }
        } else if (isE) {
            // ====== gather wave: blk n -> ebufT (transposed scatter) ======
            if (n < NBK) {
                const int pe = n & 1, t0 = n * SS;
                const int row = ln >> 3, qq = ln & 7;        // 64 tasks: 8 rows x 8 chunks
                const int tok = xidx[b * TT + t0 + row];
                const float4 v = *reinterpret_cast<const float4*>(emb + (size_t)tok * HH + qq * 4);
                float* eT = &ebufT[pe][0][0];
                eT[(4 * qq + 0) * XS + row] = v.x;
                eT[(4 * qq + 1) * XS + row] = v.y;
                eT[(4 * qq + 2) * XS + row] = v.z;
                eT[(4 * qq + 3) * XS + row] = v.w;
            }
        }
        // wv 8,9,10,12,13,14: idle
        __syncthreads();   // one barrier per 8 steps
    }

    if (isGH && ln < HH)
        out_hf[(size_t)(wv * BB + b) * HH + ln] = v_h;
}

extern "C" void kernel_launch(void* const* d_in, const int* in_sizes, int n_in,
                              void* d_out, int out_size, void* d_ws, size_t ws_size,
                              hipStream_t stream) {
    const int*   x   = (const int*)  d_in[0];
    const float* hid = (const float*)d_in[1];
    const float* emb = (const float*)d_in[2];
    const float* W1  = (const float*)d_in[3];
    const float* b1  = (const float*)d_in[4];
    const float* W2  = (const float*)d_in[5];
    const float* b2  = (const float*)d_in[6];
    const float* W3  = (const float*)d_in[7];
    const float* b3  = (const float*)d_in[8];
    const float* Wih = (const float*)d_in[9];
    const float* Whh = (const float*)d_in[10];
    const float* bih = (const float*)d_in[11];
    const float* bhh = (const float*)d_in[12];

    rnn_fused<<<dim3(BB), dim3(NT), 0, stream>>>(
        x, hid, emb, W1, b1, W2, b2, W3, b3, Wih, Whh, bih, bhh, (float*)d_out);
}

// Round 13
// 343.560 us; speedup vs baseline: 12.7262x; 12.7262x over previous
//
#include <hip/hip_runtime.h>

// Problem constants (fixed by reference)
#define BB 256      // batch
#define TT 1024     // time steps
#define HH 32       // hidden
#define SS 16       // superstep length (steps per barrier)
#define NBK (TT/SS) // 64 blocks
#define NSS (NBK+9) // 73 supersteps (10-stage skew)
#define NT 1024     // 16 waves -> 4 waves per SIMD
#define SP 32       // stream row stride (floats), 128B rows
#define GP 96       // gi row stride

// R13 = R11 (488us, best) + ONE change: gi/y waves read x via 8 uniform-address
// ds_read_b128 (broadcast) instead of 32 v_readlane per step. -38% issue on the
// feed-forward waves; register pressure kept flat (~45 VGPR) to avoid R12's
// spill blowout (5.8GB scratch FETCH). gh waves / layout / schedule unchanged.
//
// Superstep n schedule (one barrier per superstep):
//   wv12 : emb gather blk n     -> ebuf
//   wv9  : y1  blk n-1          -> y1s
//   wv10 : y2  blk n-2          -> y2s
//   wv11 : y3  blk n-3          -> y3s
//   wv3/6: gi0 A/B blk n-4      -> gib[0]
//   wv0  : gh0+gates blk n-5    -> h0s    (16 serial steps, h in regs)
//   wv4/7: gi1 A/B blk n-6      -> gib[1]
//   wv1  : gh1+gates blk n-7    -> h1s
//   wv5/8: gi2 A/B blk n-8      -> gib[2]
//   wv2  : gh2+gates blk n-9    -> out_seq (direct store)
//   wv13-15: idle (barrier only)

__device__ __forceinline__ float fast_rcp(float x) { return __builtin_amdgcn_rcpf(x); }
__device__ __forceinline__ float sigm(float x)     { return fast_rcp(1.f + __expf(-x)); }
__device__ __forceinline__ float tanh_fast(float x){ float e = __expf(2.f * x); return 1.f - 2.f * fast_rcp(e + 1.f); }
__device__ __forceinline__ float rlane(float v, int k) {
    return __int_as_float(__builtin_amdgcn_readlane(__float_as_int(v), k));
}

__global__ __launch_bounds__(NT, 4) void rnn_fused(
    const int*   __restrict__ xidx,   // [B,T]
    const float* __restrict__ hid,    // [L,B,H]
    const float* __restrict__ emb,    // [38000,H]
    const float* __restrict__ W1, const float* __restrict__ b1,
    const float* __restrict__ W2, const float* __restrict__ b2,
    const float* __restrict__ W3, const float* __restrict__ b3,
    const float* __restrict__ Wih,    // [L,3H,H]
    const float* __restrict__ Whh,    // [L,3H,H]
    const float* __restrict__ bih,    // [L,3H]
    const float* __restrict__ bhh,    // [L,3H]
    float*       __restrict__ out)    // [B*T*H] ++ [L*B*H]
{
    const int b   = blockIdx.x;
    const int tid = threadIdx.x;
    const int wv  = tid >> 6;
    const int ln  = tid & 63;
    const int lo  = ln & 31;

    __shared__ alignas(16) float ebuf[2][SS][SP];
    __shared__ alignas(16) float y1s [2][SS][SP];
    __shared__ alignas(16) float y2s [2][SS][SP];
    __shared__ alignas(16) float y3s [2][SS][SP];
    __shared__ alignas(16) float h0s [2][SS][SP];
    __shared__ alignas(16) float h1s [2][SS][SP];
    __shared__ alignas(16) float gib [3][2][SS][GP];

    // ---------------- per-role register-resident weights ----------------
    float wA[32], wB[32];
    float biasA = 0.f, biasB = 0.f, v_h = 0.f;

    if (wv < 3) {                       // gh: Whh rows {ln} and {64+lo}
        const float4* pA = reinterpret_cast<const float4*>(Whh + (size_t)(wv * 96 + ln) * HH);
        const float4* pB = reinterpret_cast<const float4*>(Whh + (size_t)(wv * 96 + 64 + lo) * HH);
        #pragma unroll
        for (int i = 0; i < 8; ++i) {
            reinterpret_cast<float4*>(wA)[i] = pA[i];
            reinterpret_cast<float4*>(wB)[i] = pB[i];
        }
        biasA = bhh[wv * 96 + ln];
        biasB = bhh[wv * 96 + 64 + lo];
        if (ln < HH) v_h = hid[(size_t)(wv * BB + b) * HH + ln];
    } else if (wv < 6) {                // giA: Wih row ln (rows 0-63)
        const int l = wv - 3;
        const float4* pA = reinterpret_cast<const float4*>(Wih + (size_t)(l * 96 + ln) * HH);
        #pragma unroll
        for (int i = 0; i < 8; ++i) reinterpret_cast<float4*>(wA)[i] = pA[i];
        biasA = bih[l * 96 + ln];
    } else if (wv < 9) {                // giB: Wih row 64+lo (rows 64-95)
        const int l = wv - 6;
        const float4* pA = reinterpret_cast<const float4*>(Wih + (size_t)(l * 96 + 64 + lo) * HH);
        #pragma unroll
        for (int i = 0; i < 8; ++i) reinterpret_cast<float4*>(wA)[i] = pA[i];
        biasA = bih[l * 96 + 64 + lo];
    } else if (wv < 12) {               // y1/y2/y3: W row lo
        const float* Ws = (wv == 9) ? W1 : (wv == 10) ? W2 : W3;
        const float* bs = (wv == 9) ? b1 : (wv == 10) ? b2 : b3;
        const float4* pA = reinterpret_cast<const float4*>(Ws + (size_t)lo * HH);
        #pragma unroll
        for (int i = 0; i < 8; ++i) reinterpret_cast<float4*>(wA)[i] = pA[i];
        biasA = bs[lo];
    }
    __syncthreads();

    float* const out_seq = out + (size_t)b * TT * HH;
    float* const out_hf  = out + (size_t)BB * TT * HH;

    for (int n = 0; n < NSS; ++n) {
        if (wv < 3) {
            // ============ gh wave, layer wv: 16 serial recurrence steps ========
            const int blk = n - 5 - 2 * wv;
            if (blk >= 0 && blk < NBK) {
                const int p = blk & 1;
                const float* gsrc = &gib[wv][p][0][0];
                for (int t2 = 0; t2 < SS; ++t2) {
                    const float giA = gsrc[t2 * GP + ln];        // r/z rows
                    const float giB = gsrc[t2 * GP + 64 + lo];   // n rows
                    float a0 = biasA, a1 = 0.f, c0 = biasB, c1 = 0.f;
                    #pragma unroll
                    for (int k = 0; k < 32; k += 2) {
                        const float h0 = rlane(v_h, k), h1 = rlane(v_h, k + 1);
                        a0 = fmaf(wA[k],     h0, a0);
                        a1 = fmaf(wA[k + 1], h1, a1);
                        c0 = fmaf(wB[k],     h0, c0);
                        c1 = fmaf(wB[k + 1], h1, c1);
                    }
                    const float sA  = giA + a0 + a1;     // r-pre / z-pre
                    const float ghB = c0 + c1;           // h_n
                    const float zp  = __shfl_xor(sA, 32);
                    const float r   = sigm(sA);
                    const float z   = sigm(zp);
                    const float nn  = tanh_fast(fmaf(r, ghB, giB));
                    const float hn  = fmaf(z, v_h - nn, nn);
                    v_h = hn;
                    if (ln < HH) {
                        if (wv == 0)      h0s[p][t2][ln] = hn;
                        else if (wv == 1) h1s[p][t2][ln] = hn;
                        else out_seq[(size_t)(blk * SS + t2) * HH + ln] = hn;
                    }
                }
            }
        } else if (wv < 6) {
            // ============ giA wave, layer l: rows 0-63, uniform-b128 broadcast =
            const int l   = wv - 3;
            const int blk = n - 4 - 2 * l;
            if (blk >= 0 && blk < NBK) {
                const int p = blk & 1;
                const float* xs = (l == 0) ? &y3s[p][0][0]
                                : (l == 1) ? &h0s[p][0][0]
                                           : &h1s[p][0][0];
                float* gdst = &gib[l][p][0][0];
                for (int t2 = 0; t2 < SS; ++t2) {
                    const float4* xr = reinterpret_cast<const float4*>(xs + t2 * SP);
                    float a0 = biasA, a1 = 0.f, a2 = 0.f, a3 = 0.f;
                    #pragma unroll
                    for (int j = 0; j < 8; ++j) {
                        const float4 xv = xr[j];          // uniform addr -> broadcast
                        a0 = fmaf(wA[4 * j + 0], xv.x, a0);
                        a1 = fmaf(wA[4 * j + 1], xv.y, a1);
                        a2 = fmaf(wA[4 * j + 2], xv.z, a2);
                        a3 = fmaf(wA[4 * j + 3], xv.w, a3);
                    }
                    gdst[t2 * GP + ln] = (a0 + a1) + (a2 + a3);
                }
            }
        } else if (wv < 9) {
            // ============ giB wave, layer l: rows 64-95 (n-gates) ==============
            const int l   = wv - 6;
            const int blk = n - 4 - 2 * l;
            if (blk >= 0 && blk < NBK) {
                const int p = blk & 1;
                const float* xs = (l == 0) ? &y3s[p][0][0]
                                : (l == 1) ? &h0s[p][0][0]
                                           : &h1s[p][0][0];
                float* gdst = &gib[l][p][0][0];
                for (int t2 = 0; t2 < SS; ++t2) {
                    const float4* xr = reinterpret_cast<const float4*>(xs + t2 * SP);
                    float a0 = biasA, a1 = 0.f, a2 = 0.f, a3 = 0.f;
                    #pragma unroll
                    for (int j = 0; j < 8; ++j) {
                        const float4 xv = xr[j];
                        a0 = fmaf(wA[4 * j + 0], xv.x, a0);
                        a1 = fmaf(wA[4 * j + 1], xv.y, a1);
                        a2 = fmaf(wA[4 * j + 2], xv.z, a2);
                        a3 = fmaf(wA[4 * j + 3], xv.w, a3);
                    }
                    if (ln < 32) gdst[t2 * GP + 64 + ln] = (a0 + a1) + (a2 + a3);
                }
            }
        } else if (wv < 12) {
            // ============ y1/y2/y3 waves =======================================
            const int s   = wv - 9;            // 0,1,2
            const int blk = n - 1 - s;
            if (blk >= 0 && blk < NBK) {
                const int p = blk & 1;
                const float* xs = (s == 0) ? &ebuf[p][0][0]
                                : (s == 1) ? &y1s[p][0][0]
                                           : &y2s[p][0][0];
                float* dst = (s == 0) ? &y1s[p][0][0]
                           : (s == 1) ? &y2s[p][0][0]
                                      : &y3s[p][0][0];
                for (int t2 = 0; t2 < SS; ++t2) {
                    const float4* xr = reinterpret_cast<const float4*>(xs + t2 * SP);
                    float a0 = biasA, a1 = 0.f, a2 = 0.f, a3 = 0.f;
                    #pragma unroll
                    for (int j = 0; j < 8; ++j) {
                        const float4 xv = xr[j];
                        a0 = fmaf(wA[4 * j + 0], xv.x, a0);
                        a1 = fmaf(wA[4 * j + 1], xv.y, a1);
                        a2 = fmaf(wA[4 * j + 2], xv.z, a2);
                        a3 = fmaf(wA[4 * j + 3], xv.w, a3);
                    }
                    const float y = fmaxf((a0 + a1) + (a2 + a3), 0.f);
                    if (ln < 32) dst[t2 * SP + ln] = y;
                }
            }
        } else if (wv == 12) {
            // ============ emb gather blk n =====================================
            if (n < NBK) {
                const int pe = n & 1, t0 = n * SS;
                #pragma unroll
                for (int k = 0; k < 2; ++k) {
                    const int task = k * 64 + ln;   // 128 tasks: 16 rows x 8 chunks
                    const int row = task >> 3, qq = task & 7;
                    const int tok = xidx[b * TT + t0 + row];
                    const float4 v = *reinterpret_cast<const float4*>(emb + (size_t)tok * HH + qq * 4);
                    *reinterpret_cast<float4*>(&ebuf[pe][row][qq * 4]) = v;
                }
            }
        }
        // wv 13-15: idle
        __syncthreads();   // one barrier per 16 steps
    }

    if (wv < 3 && ln < HH)
        out_hf[(size_t)(wv * BB + b) * HH + ln] = v_h;
}

extern "C" void kernel_launch(void* const* d_in, const int* in_sizes, int n_in,
                              void* d_out, int out_size, void* d_ws, size_t ws_size,
                              hipStream_t stream) {
    const int*   x   = (const int*)  d_in[0];
    const float* hid = (const float*)d_in[1];
    const float* emb = (const float*)d_in[2];
    const float* W1  = (const float*)d_in[3];
    const float* b1  = (const float*)d_in[4];
    const float* W2  = (const float*)d_in[5];
    const float* b2  = (const float*)d_in[6];
    const float* W3  = (const float*)d_in[7];
    const float* b3  = (const float*)d_in[8];
    const float* Wih = (const float*)d_in[9];
    const float* Whh = (const float*)d_in[10];
    const float* bih = (const float*)d_in[11];
    const float* bhh = (const float*)d_in[12];

    rnn_fused<<<dim3(BB), dim3(NT), 0, stream>>>(
        x, hid, emb, W1, b1, W2, b2, W3, b3, Wih, Whh, bih, bhh, (float*)d_out);
}